// Round 10
// baseline (155.487 us; speedup 1.0000x reference)
//
#include <hip/hip_runtime.h>

// DIAGNOSTIC ROUND. Real kernel (MODE 0) = R5-best (28.6 us) -> d_out.
// Shadow MODE 1 = same structure, grid x3 -> d_ws (forces into rocprof top-5).
// Shadow MODE 2 = MODE 1 with phase-2 LDS reads ablated to 8 token reads +
//   register rotation (same VALU/trans dataflow, un-CSE-able) -> d_ws.
// A vs B isolates the LDS-read share of the 28.6 us plateau.

constexpr int Bc = 4, Cc = 64, Hc = 96, Wc = 96;
constexpr int G = 8, OG = 8, IG = 8, KK = 7, PAD = 3;
constexpr int TH = 32, TW = 16;
constexpr int SH = TH + KK - 1;    // 38
constexpr int SWD = TW + KK - 1;   // 22
constexpr int SW2 = 25;            // float2 row stride
constexpr int TILES_H = Hc / TH, TILES_W = Wc / TW;  // 3 x 6
constexpr int TILES = TILES_H * TILES_W;             // 18
constexpr int PLANE = Hc * Wc;
constexpr int OCB = 2;
constexpr int NB = Bc * G * 4 * TILES;               // 2304
constexpr int REPS = 3;
constexpr float LOG2E = 1.4426950408889634f;

// Tap loops. HALFC literal: 0 -> emb varies with patch row i, 1 -> with col j.
#define OC_LOOP(HALFC)                                                            \
  _Pragma("unroll 1")                                                             \
  for (int oc = 0; oc < OCB; ++oc) {                                              \
    const float qv0 = qvs[oc][0], qv1 = qvs[oc][1];                               \
    float qe0[KK], qe1[KK];                                                       \
    _Pragma("unroll")                                                             \
    for (int t = 0; t < KK; ++t) {                                                \
      const float e = eb[oc * KK + t];                                            \
      qe0[t] = qv0 * e; qe1[t] = qv1 * e;                                         \
    }                                                                             \
    float s0a = 0.f, s0b = 0.f, o0a = 0.f, o0b = 0.f;                             \
    float s1a = 0.f, s1b = 0.f, o1a = 0.f, o1b = 0.f;                             \
    const float2* rp = &kvs[oc][r0][tx];                                          \
    _Pragma("unroll")                                                             \
    for (int i = 0; i < 8; ++i) {                                                 \
      float2 row[KK];                                                             \
      if constexpr (MODE == 2) {                                                  \
        _Pragma("unroll")                                                         \
        for (int j = 0; j < KK; ++j) row[j] = rowc[(i + j) & 7];                  \
      } else {                                                                    \
        _Pragma("unroll")                                                         \
        for (int j = 0; j < KK; ++j) row[j] = rp[i * SW2 + j];                    \
      }                                                                           \
      if (i < 7) {                                                                \
        _Pragma("unroll")                                                         \
        for (int j = 0; j < KK; ++j) {                                            \
          const float ev = __builtin_amdgcn_exp2f(                                \
              fmaf(qv0, row[j].x, (HALFC) ? qe0[j] : qe0[i]));                    \
          if (j & 1) { s0b += ev; o0b = fmaf(ev, row[j].y, o0b); }                \
          else       { s0a += ev; o0a = fmaf(ev, row[j].y, o0a); }                \
        }                                                                         \
      }                                                                           \
      if (i >= 1) {                                                               \
        _Pragma("unroll")                                                         \
        for (int j = 0; j < KK; ++j) {                                            \
          const float ev = __builtin_amdgcn_exp2f(                                \
              fmaf(qv1, row[j].x, (HALFC) ? qe1[j] : qe1[i - 1]));                \
          if (j & 1) { s1b += ev; o1b = fmaf(ev, row[j].y, o1b); }                \
          else       { s1a += ev; o1a = fmaf(ev, row[j].y, o1a); }                \
        }                                                                         \
      }                                                                           \
    }                                                                             \
    ob[oc * PLANE]      = (o0a + o0b) * __builtin_amdgcn_rcpf(s0a + s0b);         \
    ob[oc * PLANE + Wc] = (o1a + o1b) * __builtin_amdgcn_rcpf(s1a + s1b);         \
  }

template<int MODE>
__global__ __launch_bounds__(256, 8)
void sasa_kernel(const float* __restrict__ x,
                 const float* __restrict__ wq,
                 const float* __restrict__ wk,
                 const float* __restrict__ wv,
                 const float* __restrict__ h_emb,
                 const float* __restrict__ w_emb,
                 float* __restrict__ outp)
{
    __shared__ float2 kvs[OCB][SH][SW2];   // 15200 B

    const int tid = threadIdx.x;
    const int lb  = (MODE == 0) ? (int)blockIdx.x : (int)(blockIdx.x % NB);
    // XCD-aware bijective swizzle within each generation.
    const int L = (lb & 7) * (NB / 8) + (lb >> 3);
    const int tile    = L % TILES;
    const int rest    = L / TILES;
    const int quarter = rest & 3;
    const int gi      = (rest >> 2) & 7;
    const int b       = rest >> 5;
    const int half    = quarter >> 1;
    const int th0     = (tile / TILES_W) * TH;
    const int tw0     = (tile % TILES_W) * TW;

    const float* xb  = x  + (size_t)(b * Cc + gi * IG) * PLANE;
    const float* wqg = wq + gi * OG * IG + quarter * OCB * IG;
    const float* wkg = wk + gi * OG * IG + quarter * OCB * IG;
    const float* wvg = wv + gi * OG * IG + quarter * OCB * IG;
    const float* eb  = (half ? w_emb : h_emb) + gi * (OG / 2) * KK
                                              + (quarter & 1) * OCB * KK;

    const int tx = tid & 15;
    const int r0 = 2 * (tid >> 4);
    const int h0 = th0 + r0;
    const int wg = tw0 + tx;
    float xc0[IG], xc1[IG];
    {
        const float* xp = xb + (size_t)h0 * Wc + wg;
        #pragma unroll
        for (int i = 0; i < IG; ++i) {
            xc0[i] = xp[i * PLANE];
            xc1[i] = xp[i * PLANE + Wc];
        }
    }

    // Phase 1: k,v conv -> LDS
    for (int e = tid; e < SH * SWD; e += 256) {
        const int hy = e / SWD, hx = e - hy * SWD;
        const int gy = th0 + hy - PAD;
        const int gx = tw0 + hx - PAD;
        const bool valid = ((unsigned)gy < (unsigned)Hc) && ((unsigned)gx < (unsigned)Wc);
        float xv[IG];
        #pragma unroll
        for (int i = 0; i < IG; ++i)
            xv[i] = valid ? xb[i * PLANE + gy * Wc + gx] : 0.0f;
        #pragma unroll
        for (int oc = 0; oc < OCB; ++oc) {
            float ka = 0.f, va = 0.f;
            #pragma unroll
            for (int i = 0; i < IG; ++i) {
                ka = fmaf(xv[i], wkg[oc * IG + i], ka);
                va = fmaf(xv[i], wvg[oc * IG + i], va);
            }
            kvs[oc][hy][hx] = make_float2(ka, va);
        }
    }

    float qvs[OCB][2];
    #pragma unroll
    for (int oc = 0; oc < OCB; ++oc) {
        float q0 = 0.f, q1 = 0.f;
        #pragma unroll
        for (int i = 0; i < IG; ++i) {
            const float wqi = wqg[oc * IG + i];
            q0 = fmaf(xc0[i], wqi, q0);
            q1 = fmaf(xc1[i], wqi, q1);
        }
        qvs[oc][0] = q0 * LOG2E;
        qvs[oc][1] = q1 * LOG2E;
    }
    __syncthreads();

    // MODE 2: 8 token LDS reads (real data, keeps writes live, defeats CSE).
    float2 rowc[8];
    if constexpr (MODE == 2) {
        #pragma unroll
        for (int j = 0; j < 8; ++j) rowc[j] = kvs[0][j][tx];
    }

    float* ob = outp + (size_t)(b * Cc + gi * OG + quarter * OCB) * PLANE
                     + (size_t)h0 * Wc + wg;

    if (half == 0) { OC_LOOP(0) } else { OC_LOOP(1) }
}

extern "C" void kernel_launch(void* const* d_in, const int* in_sizes, int n_in,
                              void* d_out, int out_size, void* d_ws, size_t ws_size,
                              hipStream_t stream)
{
    const float* x     = (const float*)d_in[0];
    const float* wq    = (const float*)d_in[1];
    const float* wk    = (const float*)d_in[2];
    const float* wv    = (const float*)d_in[3];
    const float* h_emb = (const float*)d_in[4];
    const float* w_emb = (const float*)d_in[5];
    float* out = (float*)d_out;

    float* wsA = (float*)d_ws;                         // 9.44 MB shadow target A
    float* wsB = wsA + (size_t)Bc * Cc * PLANE;        // shadow target B

    // Real result (28.6 us class)
    sasa_kernel<0><<<NB, 256, 0, stream>>>(x, wq, wk, wv, h_emb, w_emb, out);
    // Shadow A: full structure, x3 grid -> top-5 counters
    sasa_kernel<1><<<NB * REPS, 256, 0, stream>>>(x, wq, wk, wv, h_emb, w_emb, wsA);
    // Shadow B: LDS-read-ablated, x3 grid
    sasa_kernel<2><<<NB * REPS, 256, 0, stream>>>(x, wq, wk, wv, h_emb, w_emb, wsB);
}

// Round 11
// 34.151 us; speedup vs baseline: 4.5529x; 4.5529x over previous
//
#include <hip/hip_runtime.h>

// SASA local self-attention, fully fused, f32 I/O.
// B=4, C=64, H=W=96, g=8, og=ig=8, k=7, pad=3.
// Block = (b, group, channel-quarter) x 32x16 tile; 2 output channels/block.
// 256 threads, each owns 2 vertically-adjacent pixels.
// R10 ablation: phase-2 ds_read_b64 stream = 16 of the 28.6 us (the wall).
// -> k,v stored BF16-packed: uint2 = (k0|v0<<16, k1|v1<<16); ONE ds_read_b64
//    per tap serves BOTH channels: 112 -> 56 LDS insts/thread, bytes halved.
// Element 8 B, row stride 23 (odd) -> balanced 4 words/bank (no conflicts).
// Unpack = lshl/and (bf16 -> f32 is a 16-bit shift). e-values live in SGPRs.
// exp2-prescaled softmax, no max-subtraction (|logit|*log2e << 127).
// XCD-aware bijective block swizzle (2304 % 8 == 0).

constexpr int Bc = 4, Cc = 64, Hc = 96, Wc = 96;
constexpr int G = 8, OG = 8, IG = 8, KK = 7, PAD = 3;
constexpr int TH = 32, TW = 16;
constexpr int SH = TH + KK - 1;    // 38 halo rows
constexpr int SWD = TW + KK - 1;   // 22 halo cols (data)
constexpr int SWP = 23;            // LDS row stride in uint2 (odd)
constexpr int TILES_H = Hc / TH, TILES_W = Wc / TW;  // 3 x 6
constexpr int TILES = TILES_H * TILES_W;             // 18
constexpr int PLANE = Hc * Wc;
constexpr int OCB = 2;             // output channels per block (4 quarters)
constexpr int NB = Bc * G * 4 * TILES;               // 2304
constexpr float LOG2E = 1.4426950408889634f;

__device__ __forceinline__ unsigned pk2(float k, float v) {
    // RNE-rounded bf16 pair: k in low half, v in high half.
    unsigned uk = __builtin_bit_cast(unsigned, k);
    unsigned uv = __builtin_bit_cast(unsigned, v);
    uk = (uk + 0x7fffu + ((uk >> 16) & 1u)) >> 16;
    uv = (uv + 0x7fffu + ((uv >> 16) & 1u)) & 0xffff0000u;
    return (uk & 0xffffu) | uv;
}
__device__ __forceinline__ float lo2f(unsigned u) {
    return __builtin_bit_cast(float, u << 16);
}
__device__ __forceinline__ float hi2f(unsigned u) {
    return __builtin_bit_cast(float, u & 0xffff0000u);
}

// Tap loops. HALFC literal: 0 -> emb varies with patch row i, 1 -> with col j.
// Streams: (oc0,px0)(oc1,px0)(oc0,px1)(oc1,px1); px0 rows i=0..6, px1 i=1..7.
#define PHASE2(HALFC)                                                             \
  {                                                                               \
    float s00 = 0.f, s10 = 0.f, o00 = 0.f, o10 = 0.f;  /* px0: oc0, oc1 */        \
    float s01 = 0.f, s11 = 0.f, o01 = 0.f, o11 = 0.f;  /* px1 */                  \
    const uint2* rp = &kvs[r0][tx];                                               \
    _Pragma("unroll")                                                             \
    for (int i = 0; i < 8; ++i) {                                                 \
      uint2 row[KK];                                                              \
      _Pragma("unroll")                                                           \
      for (int j = 0; j < KK; ++j) row[j] = rp[i * SWP + j];                      \
      _Pragma("unroll")                                                           \
      for (int j = 0; j < KK; ++j) {                                              \
        const float k0 = lo2f(row[j].x), v0 = hi2f(row[j].x);                     \
        const float k1 = lo2f(row[j].y), v1 = hi2f(row[j].y);                     \
        if (i < 7) {                                                              \
          const float t0 = k0 + e0[(HALFC) ? j : i];                              \
          const float t1 = k1 + e1[(HALFC) ? j : i];                              \
          const float a0 = __builtin_amdgcn_exp2f(qv00 * t0);                     \
          const float a1 = __builtin_amdgcn_exp2f(qv10 * t1);                     \
          s00 += a0; o00 = fmaf(a0, v0, o00);                                     \
          s10 += a1; o10 = fmaf(a1, v1, o10);                                     \
        }                                                                         \
        if (i >= 1) {                                                             \
          const float t0 = k0 + e0[(HALFC) ? j : (i - 1)];                        \
          const float t1 = k1 + e1[(HALFC) ? j : (i - 1)];                        \
          const float a0 = __builtin_amdgcn_exp2f(qv01 * t0);                     \
          const float a1 = __builtin_amdgcn_exp2f(qv11 * t1);                     \
          s01 += a0; o01 = fmaf(a0, v0, o01);                                     \
          s11 += a1; o11 = fmaf(a1, v1, o11);                                     \
        }                                                                         \
      }                                                                           \
    }                                                                             \
    ob[0]           = o00 * __builtin_amdgcn_rcpf(s00);                           \
    ob[Wc]          = o01 * __builtin_amdgcn_rcpf(s01);                           \
    ob[PLANE]       = o10 * __builtin_amdgcn_rcpf(s10);                           \
    ob[PLANE + Wc]  = o11 * __builtin_amdgcn_rcpf(s11);                           \
  }

__global__ __launch_bounds__(256)
void sasa_kernel(const float* __restrict__ x,
                 const float* __restrict__ wq,
                 const float* __restrict__ wk,
                 const float* __restrict__ wv,
                 const float* __restrict__ h_emb,
                 const float* __restrict__ w_emb,
                 float* __restrict__ out)
{
    __shared__ uint2 kvs[SH][SWP];     // 6992 B

    const int tid = threadIdx.x;
    // XCD-aware bijective swizzle: each XCD owns 288 consecutive logical blocks.
    const int L = (blockIdx.x & 7) * (NB / 8) + (blockIdx.x >> 3);
    const int tile    = L % TILES;
    const int rest    = L / TILES;
    const int quarter = rest & 3;      // oc_global = quarter*2 + {0,1}
    const int gi      = (rest >> 2) & 7;
    const int b       = rest >> 5;
    const int half    = quarter >> 1;  // 0 -> h_emb, 1 -> w_emb
    const int th0     = (tile / TILES_W) * TH;
    const int tw0     = (tile % TILES_W) * TW;

    const float* xb  = x  + (size_t)(b * Cc + gi * IG) * PLANE;
    const float* wqg = wq + gi * OG * IG + quarter * OCB * IG;  // block-uniform
    const float* wkg = wk + gi * OG * IG + quarter * OCB * IG;
    const float* wvg = wv + gi * OG * IG + quarter * OCB * IG;
    const float* eb  = (half ? w_emb : h_emb) + gi * (OG / 2) * KK
                                              + (quarter & 1) * OCB * KK;

    // emb values: block-uniform -> SGPRs.
    float e0[KK], e1[KK];
    #pragma unroll
    for (int t = 0; t < KK; ++t) { e0[t] = eb[t]; e1[t] = eb[KK + t]; }

    // ---- q-pixel loads issued first so HBM latency hides under phase 1 ----
    const int tx = tid & 15;
    const int r0 = 2 * (tid >> 4);     // local rows r0, r0+1
    const int h0 = th0 + r0;
    const int wg = tw0 + tx;
    float xc0[IG], xc1[IG];
    {
        const float* xp = xb + (size_t)h0 * Wc + wg;
        #pragma unroll
        for (int i = 0; i < IG; ++i) {
            xc0[i] = xp[i * PLANE];
            xc1[i] = xp[i * PLANE + Wc];
        }
    }

    // ---- Phase 1: k,v (grouped 1x1 conv) over 38x22 halo -> bf16-packed LDS ----
    for (int e = tid; e < SH * SWD; e += 256) {
        const int hy = e / SWD, hx = e - hy * SWD;
        const int gy = th0 + hy - PAD;
        const int gx = tw0 + hx - PAD;
        const bool valid = ((unsigned)gy < (unsigned)Hc) && ((unsigned)gx < (unsigned)Wc);
        float xv[IG];
        #pragma unroll
        for (int i = 0; i < IG; ++i)
            xv[i] = valid ? xb[i * PLANE + gy * Wc + gx] : 0.0f;
        float k0 = 0.f, v0 = 0.f, k1 = 0.f, v1 = 0.f;
        #pragma unroll
        for (int i = 0; i < IG; ++i) {
            k0 = fmaf(xv[i], wkg[i],      k0);
            v0 = fmaf(xv[i], wvg[i],      v0);
            k1 = fmaf(xv[i], wkg[IG + i], k1);
            v1 = fmaf(xv[i], wvg[IG + i], v1);
        }
        kvs[hy][hx] = make_uint2(pk2(k0, v0), pk2(k1, v1));
    }

    // q projections before the barrier; xc registers retire here.
    float qv00, qv01, qv10, qv11;      // qv[oc][px]
    {
        float a0 = 0.f, a1 = 0.f, b0 = 0.f, b1 = 0.f;
        #pragma unroll
        for (int i = 0; i < IG; ++i) {
            const float w0 = wqg[i], w1 = wqg[IG + i];
            a0 = fmaf(xc0[i], w0, a0);
            a1 = fmaf(xc1[i], w0, a1);
            b0 = fmaf(xc0[i], w1, b0);
            b1 = fmaf(xc1[i], w1, b1);
        }
        qv00 = a0 * LOG2E; qv01 = a1 * LOG2E;
        qv10 = b0 * LOG2E; qv11 = b1 * LOG2E;
    }
    __syncthreads();

    // ---- Phase 2: attention; thread owns pixels (r0, tx) and (r0+1, tx) ----
    float* ob = out + (size_t)(b * Cc + gi * OG + quarter * OCB) * PLANE
                    + (size_t)h0 * Wc + wg;

    if (half == 0) { PHASE2(0) } else { PHASE2(1) }
}

extern "C" void kernel_launch(void* const* d_in, const int* in_sizes, int n_in,
                              void* d_out, int out_size, void* d_ws, size_t ws_size,
                              hipStream_t stream)
{
    const float* x     = (const float*)d_in[0];
    const float* wq    = (const float*)d_in[1];
    const float* wk    = (const float*)d_in[2];
    const float* wv    = (const float*)d_in[3];
    const float* h_emb = (const float*)d_in[4];
    const float* w_emb = (const float*)d_in[5];
    float* out = (float*)d_out;

    sasa_kernel<<<NB, 256, 0, stream>>>(x, wq, wk, wv, h_emb, w_emb, out);
}

// Round 12
// 32.665 us; speedup vs baseline: 4.7600x; 1.0455x over previous
//
#include <hip/hip_runtime.h>

// SASA local self-attention, fully fused, f32 I/O.
// B=4, C=64, H=W=96, g=8, og=ig=8, k=7, pad=3.
// Block = (b, group, channel-quarter) x 32x16 tile; 2 output channels/block.
// 256 threads, each owns 2 vertically-adjacent pixels.
// R10 ablation: phase-2 LDS-read stream is the wall (~17 of 28.6 us, ~44 eff
// cyc per ds_read_b64 = convoy/latency, not bandwidth). This round:
//  - k,v bf16-packed uint2 (k0|v0<<16, k1|v1<<16): ONE b64/tap for BOTH oc.
//  - fmaf(qv, k, qe) form kept (qe = qv*e precomputed): 20 VALU/tap.
//  - explicit row prefetch (cur/nxt reg double-buffer) to hide read latency
//    under the 28-taps-per-row compute instead of lockstep batch-drain.
// Row stride 23 uint2 (odd) -> balanced banks, 2-way free.
// exp2-prescaled softmax, no max-subtraction. XCD-aware bijective swizzle.

constexpr int Bc = 4, Cc = 64, Hc = 96, Wc = 96;
constexpr int G = 8, OG = 8, IG = 8, KK = 7, PAD = 3;
constexpr int TH = 32, TW = 16;
constexpr int SH = TH + KK - 1;    // 38 halo rows
constexpr int SWD = TW + KK - 1;   // 22 halo cols (data)
constexpr int SWP = 23;            // LDS row stride in uint2 (odd)
constexpr int TILES_H = Hc / TH, TILES_W = Wc / TW;  // 3 x 6
constexpr int TILES = TILES_H * TILES_W;             // 18
constexpr int PLANE = Hc * Wc;
constexpr int OCB = 2;             // output channels per block (4 quarters)
constexpr int NB = Bc * G * 4 * TILES;               // 2304
constexpr float LOG2E = 1.4426950408889634f;

__device__ __forceinline__ unsigned pk2(float k, float v) {
    // RNE-rounded bf16 pair: k in low half, v in high half.
    unsigned uk = __builtin_bit_cast(unsigned, k);
    unsigned uv = __builtin_bit_cast(unsigned, v);
    uk = (uk + 0x7fffu + ((uk >> 16) & 1u)) >> 16;
    uv = (uv + 0x7fffu + ((uv >> 16) & 1u)) & 0xffff0000u;
    return (uk & 0xffffu) | uv;
}
__device__ __forceinline__ float lo2f(unsigned u) {
    return __builtin_bit_cast(float, u << 16);
}
__device__ __forceinline__ float hi2f(unsigned u) {
    return __builtin_bit_cast(float, u & 0xffff0000u);
}

// Tap loops. HALFC literal: 0 -> emb varies with patch row i, 1 -> with col j.
// Streams: (oc0,px0)(oc1,px0)(oc0,px1)(oc1,px1); px0 rows i=0..6, px1 i=1..7.
#define PHASE2(HALFC)                                                             \
  {                                                                               \
    float s00 = 0.f, s10 = 0.f, o00 = 0.f, o10 = 0.f;  /* px0: oc0, oc1 */        \
    float s01 = 0.f, s11 = 0.f, o01 = 0.f, o11 = 0.f;  /* px1 */                  \
    const uint2* rp = &kvs[r0][tx];                                               \
    uint2 cur[KK], nxt[KK];                                                       \
    _Pragma("unroll")                                                             \
    for (int j = 0; j < KK; ++j) cur[j] = rp[j];                                  \
    _Pragma("unroll")                                                             \
    for (int i = 0; i < 8; ++i) {                                                 \
      if (i < 7) {                                                                \
        _Pragma("unroll")                                                         \
        for (int j = 0; j < KK; ++j) nxt[j] = rp[(i + 1) * SWP + j];              \
      }                                                                           \
      _Pragma("unroll")                                                           \
      for (int j = 0; j < KK; ++j) {                                              \
        const float k0 = lo2f(cur[j].x), v0 = hi2f(cur[j].x);                     \
        const float k1 = lo2f(cur[j].y), v1 = hi2f(cur[j].y);                     \
        if (i < 7) {                                                              \
          const float a0 = __builtin_amdgcn_exp2f(                                \
              fmaf(qv00, k0, qe00[(HALFC) ? j : i]));                             \
          const float a1 = __builtin_amdgcn_exp2f(                                \
              fmaf(qv10, k1, qe10[(HALFC) ? j : i]));                             \
          s00 += a0; o00 = fmaf(a0, v0, o00);                                     \
          s10 += a1; o10 = fmaf(a1, v1, o10);                                     \
        }                                                                         \
        if (i >= 1) {                                                             \
          const float a0 = __builtin_amdgcn_exp2f(                                \
              fmaf(qv01, k0, qe01[(HALFC) ? j : (i - 1)]));                       \
          const float a1 = __builtin_amdgcn_exp2f(                                \
              fmaf(qv11, k1, qe11[(HALFC) ? j : (i - 1)]));                       \
          s01 += a0; o01 = fmaf(a0, v0, o01);                                     \
          s11 += a1; o11 = fmaf(a1, v1, o11);                                     \
        }                                                                         \
      }                                                                           \
      if (i < 7) {                                                                \
        _Pragma("unroll")                                                         \
        for (int j = 0; j < KK; ++j) cur[j] = nxt[j];                             \
      }                                                                           \
    }                                                                             \
    ob[0]          = o00 * __builtin_amdgcn_rcpf(s00);                            \
    ob[Wc]         = o01 * __builtin_amdgcn_rcpf(s01);                            \
    ob[PLANE]      = o10 * __builtin_amdgcn_rcpf(s10);                            \
    ob[PLANE + Wc] = o11 * __builtin_amdgcn_rcpf(s11);                            \
  }

__global__ __launch_bounds__(256)
void sasa_kernel(const float* __restrict__ x,
                 const float* __restrict__ wq,
                 const float* __restrict__ wk,
                 const float* __restrict__ wv,
                 const float* __restrict__ h_emb,
                 const float* __restrict__ w_emb,
                 float* __restrict__ out)
{
    __shared__ uint2 kvs[SH][SWP];     // 6992 B

    const int tid = threadIdx.x;
    // XCD-aware bijective swizzle: each XCD owns 288 consecutive logical blocks.
    const int L = (blockIdx.x & 7) * (NB / 8) + (blockIdx.x >> 3);
    const int tile    = L % TILES;
    const int rest    = L / TILES;
    const int quarter = rest & 3;      // oc_global = quarter*2 + {0,1}
    const int gi      = (rest >> 2) & 7;
    const int b       = rest >> 5;
    const int half    = quarter >> 1;  // 0 -> h_emb, 1 -> w_emb
    const int th0     = (tile / TILES_W) * TH;
    const int tw0     = (tile % TILES_W) * TW;

    const float* xb  = x  + (size_t)(b * Cc + gi * IG) * PLANE;
    const float* wqg = wq + gi * OG * IG + quarter * OCB * IG;  // block-uniform
    const float* wkg = wk + gi * OG * IG + quarter * OCB * IG;
    const float* wvg = wv + gi * OG * IG + quarter * OCB * IG;
    const float* eb  = (half ? w_emb : h_emb) + gi * (OG / 2) * KK
                                              + (quarter & 1) * OCB * KK;

    // ---- q-pixel loads issued first so HBM latency hides under phase 1 ----
    const int tx = tid & 15;
    const int r0 = 2 * (tid >> 4);     // local rows r0, r0+1
    const int h0 = th0 + r0;
    const int wg = tw0 + tx;
    float xc0[IG], xc1[IG];
    {
        const float* xp = xb + (size_t)h0 * Wc + wg;
        #pragma unroll
        for (int i = 0; i < IG; ++i) {
            xc0[i] = xp[i * PLANE];
            xc1[i] = xp[i * PLANE + Wc];
        }
    }

    // ---- Phase 1: k,v (grouped 1x1 conv) over 38x22 halo -> bf16-packed LDS ----
    for (int e = tid; e < SH * SWD; e += 256) {
        const int hy = e / SWD, hx = e - hy * SWD;
        const int gy = th0 + hy - PAD;
        const int gx = tw0 + hx - PAD;
        const bool valid = ((unsigned)gy < (unsigned)Hc) && ((unsigned)gx < (unsigned)Wc);
        float xv[IG];
        #pragma unroll
        for (int i = 0; i < IG; ++i)
            xv[i] = valid ? xb[i * PLANE + gy * Wc + gx] : 0.0f;
        float k0 = 0.f, v0 = 0.f, k1 = 0.f, v1 = 0.f;
        #pragma unroll
        for (int i = 0; i < IG; ++i) {
            k0 = fmaf(xv[i], wkg[i],      k0);
            v0 = fmaf(xv[i], wvg[i],      v0);
            k1 = fmaf(xv[i], wkg[IG + i], k1);
            v1 = fmaf(xv[i], wvg[IG + i], v1);
        }
        kvs[hy][hx] = make_uint2(pk2(k0, v0), pk2(k1, v1));
    }

    // q projections + qe = qv*e precompute before the barrier; xc regs retire.
    float qv00, qv01, qv10, qv11;      // qv[oc][px]
    {
        float a0 = 0.f, a1 = 0.f, b0 = 0.f, b1 = 0.f;
        #pragma unroll
        for (int i = 0; i < IG; ++i) {
            const float w0 = wqg[i], w1 = wqg[IG + i];
            a0 = fmaf(xc0[i], w0, a0);
            a1 = fmaf(xc1[i], w0, a1);
            b0 = fmaf(xc0[i], w1, b0);
            b1 = fmaf(xc1[i], w1, b1);
        }
        qv00 = a0 * LOG2E; qv01 = a1 * LOG2E;
        qv10 = b0 * LOG2E; qv11 = b1 * LOG2E;
    }
    float qe00[KK], qe01[KK], qe10[KK], qe11[KK];
    #pragma unroll
    for (int t = 0; t < KK; ++t) {
        const float e0 = eb[t], e1 = eb[KK + t];
        qe00[t] = qv00 * e0; qe01[t] = qv01 * e0;
        qe10[t] = qv10 * e1; qe11[t] = qv11 * e1;
    }
    __syncthreads();

    // ---- Phase 2: attention; thread owns pixels (r0, tx) and (r0+1, tx) ----
    float* ob = out + (size_t)(b * Cc + gi * OG + quarter * OCB) * PLANE
                    + (size_t)h0 * Wc + wg;

    if (half == 0) { PHASE2(0) } else { PHASE2(1) }
}

extern "C" void kernel_launch(void* const* d_in, const int* in_sizes, int n_in,
                              void* d_out, int out_size, void* d_ws, size_t ws_size,
                              hipStream_t stream)
{
    const float* x     = (const float*)d_in[0];
    const float* wq    = (const float*)d_in[1];
    const float* wk    = (const float*)d_in[2];
    const float* wv    = (const float*)d_in[3];
    const float* h_emb = (const float*)d_in[4];
    const float* w_emb = (const float*)d_in[5];
    float* out = (float*)d_out;

    sasa_kernel<<<NB, 256, 0, stream>>>(x, wq, wk, wv, h_emb, w_emb, out);
}